// Round 3
// baseline (430.768 us; speedup 1.0000x reference)
//
#include <hip/hip_runtime.h>

#define NXD 512
#define NYD 512
#define CD  64
#define NPIX (NXD * NYD)          // 262144 slots per batch image
// Problem constants fixed by the reference: B=4, C=64, NX=NY=512.

// Init winner array to -1 (int4 stores). 4 MiB -> ~2 us.
__global__ void ppscatter_init_winner(int4* __restrict__ win4, int n_win4) {
    int i = blockIdx.x * blockDim.x + threadIdx.x;
    if (i < n_win4) win4[i] = make_int4(-1, -1, -1, -1);
}

// Last-write-wins vote: max voxel index per flat slot wins (matches numpy
// fancy-assignment last-duplicate-wins; verified absmax=0.0 in rounds 1-2).
__global__ void ppscatter_vote(const int* __restrict__ coords, int n,
                               int* __restrict__ winner) {
    int v = blockIdx.x * blockDim.x + threadIdx.x;
    if (v >= n) return;
    int b = coords[3 * v + 0];
    int x = coords[3 * v + 1];
    int y = coords[3 * v + 2];
    atomicMax(&winner[b * NPIX + x * NYD + y], v);
}

// Gather: one thread per (b, x, y4) pixel-group; sweeps all 64 channels.
//   i bits: y4 [0:6], x [7:15], b [16:17]  ->  win4 index == i exactly.
//   out4 index for channel c: (b<<22) | (c<<16) | (x<<7) | y4.
// winner read ONCE (4 MB total, vs ~268 MB logical re-read in round 2);
// feat rows read as coalesced float4 (16 loads/row); stores 1 KB/wave.
__global__ void ppscatter_gather(const float4* __restrict__ feat4,
                                 const int4* __restrict__ win4,
                                 float4* __restrict__ out4) {
    int i = blockIdx.x * blockDim.x + threadIdx.x;   // 0 .. 262143
    int4 w = win4[i];
    int base = ((i >> 16) << 22) | (i & 0xFFFF);     // channel-0 out4 index

    if ((w.x & w.y & w.z & w.w) == -1) {
        // All 4 pixels empty (~74% of threads): pure zero-fill.
        const float4 z = make_float4(0.f, 0.f, 0.f, 0.f);
        #pragma unroll 8
        for (int c = 0; c < CD; ++c) out4[base + (c << 16)] = z;
    } else {
        const float4 z = make_float4(0.f, 0.f, 0.f, 0.f);
        #pragma unroll 2
        for (int g = 0; g < CD / 4; ++g) {           // channels 4g .. 4g+3
            float4 fx = (w.x >= 0) ? feat4[w.x * 16 + g] : z;
            float4 fy = (w.y >= 0) ? feat4[w.y * 16 + g] : z;
            float4 fz = (w.z >= 0) ? feat4[w.z * 16 + g] : z;
            float4 fw = (w.w >= 0) ? feat4[w.w * 16 + g] : z;
            // 4x4 register transpose: row-major feat -> channel-major out.
            out4[base + ((4 * g + 0) << 16)] = make_float4(fx.x, fy.x, fz.x, fw.x);
            out4[base + ((4 * g + 1) << 16)] = make_float4(fx.y, fy.y, fz.y, fw.y);
            out4[base + ((4 * g + 2) << 16)] = make_float4(fx.z, fy.z, fz.z, fw.z);
            out4[base + ((4 * g + 3) << 16)] = make_float4(fx.w, fy.w, fz.w, fw.w);
        }
    }
}

extern "C" void kernel_launch(void* const* d_in, const int* in_sizes, int n_in,
                              void* d_out, int out_size, void* d_ws, size_t ws_size,
                              hipStream_t stream) {
    const float* feat  = (const float*)d_in[0];
    const int* coords  = (const int*)d_in[1];

    int n = in_sizes[1] / 3;            // 80000 voxels
    int* winner = (int*)d_ws;           // B*NX*NY ints = 4 MiB scratch

    const int T = 256;
    int B = out_size / (CD * NPIX);     // 4

    int n_win4 = (B * NPIX) / 4;        // 262144
    ppscatter_init_winner<<<(n_win4 + T - 1) / T, T, 0, stream>>>((int4*)winner, n_win4);

    ppscatter_vote<<<(n + T - 1) / T, T, 0, stream>>>(coords, n, winner);

    int n_groups = (B * NPIX) / 4;      // 262144 pixel-groups
    ppscatter_gather<<<n_groups / T, T, 0, stream>>>((const float4*)feat,
                                                     (const int4*)winner,
                                                     (float4*)d_out);
}

// Round 5
// 288.940 us; speedup vs baseline: 1.4909x; 1.4909x over previous
//
#include <hip/hip_runtime.h>

#define NXD 512
#define NYD 512
#define CD  64
#define NPIX (NXD * NYD)
// Problem constants fixed by the reference: B=4, C=64, NX=NY=512.
//
// Round-3 lesson (measured): one-thread-per-out4 with linear streaming stores
// (R2, kernels ~79 us) beats per-pixel channel sweeps with 1 MiB-strided
// stores (R3, kernels ~155 us). Harness poison fills (~215-275 us) sit inside
// the timed window — compare kernel-side time, not headline dur_us.
//
// Round-4 lesson: __builtin_nontemporal_store needs a NATIVE vector type,
// not HIP's float4 class. Use ext_vector_type(4).

typedef float nfloat4 __attribute__((ext_vector_type(4)));

// Init winner array to -1 (int4 stores). 4 MiB.
__global__ void ppscatter_init_winner(int4* __restrict__ win4, int n_win4) {
    int i = blockIdx.x * blockDim.x + threadIdx.x;
    if (i < n_win4) win4[i] = make_int4(-1, -1, -1, -1);
}

// Last-write-wins vote: max voxel index per flat slot wins (matches numpy
// fancy-assignment last-duplicate-wins; verified absmax=0.0 rounds 1-3).
__global__ void ppscatter_vote(const int* __restrict__ coords, int n,
                               int* __restrict__ winner) {
    int v = blockIdx.x * blockDim.x + threadIdx.x;
    if (v >= n) return;
    int b = coords[3 * v + 0];
    int x = coords[3 * v + 1];
    int y = coords[3 * v + 2];
    atomicMax(&winner[b * NPIX + x * NYD + y], v);
}

// Gather: one thread per output float4, linear mapping (i -> out4[i]).
//   i bits: y4 [0:6], x [7:15], c [16:21], b [22:23].
// Stores: 1 KB/wave, fully contiguous across the grid (streaming-optimal),
// and NON-TEMPORAL so the 268 MB write stream doesn't evict winner (4 MB)
// and feat (20 MB) from L2 — those are re-read across the 64 channel sweeps.
__global__ void ppscatter_gather(const float* __restrict__ feat,
                                 const int* __restrict__ winner,
                                 nfloat4* __restrict__ out4) {
    int i = blockIdx.x * blockDim.x + threadIdx.x;  // 16,777,216 threads
    int c  = (i >> 16) & 63;
    int b  = i >> 22;

    const int4* win4 = (const int4*)winner;
    int4 w = win4[(b << 16) | (i & 0xFFFF)];        // winner[b][x][4*y4 ..]

    nfloat4 val = {0.f, 0.f, 0.f, 0.f};
    // Empty fast path: entries are -1 or >=0; AND == -1 iff all empty (~74%).
    if ((w.x & w.y & w.z & w.w) != -1) {
        if (w.x >= 0) val.x = feat[(w.x << 6) + c];
        if (w.y >= 0) val.y = feat[(w.y << 6) + c];
        if (w.z >= 0) val.z = feat[(w.z << 6) + c];
        if (w.w >= 0) val.w = feat[(w.w << 6) + c];
    }
    __builtin_nontemporal_store(val, &out4[i]);
}

extern "C" void kernel_launch(void* const* d_in, const int* in_sizes, int n_in,
                              void* d_out, int out_size, void* d_ws, size_t ws_size,
                              hipStream_t stream) {
    const float* feat  = (const float*)d_in[0];
    const int* coords  = (const int*)d_in[1];

    int n = in_sizes[1] / 3;            // 80000 voxels
    int* winner = (int*)d_ws;           // B*NX*NY ints = 4 MiB scratch

    const int T = 256;
    int B = out_size / (CD * NPIX);     // 4

    int n_win4 = (B * NPIX) / 4;        // 262144
    ppscatter_init_winner<<<(n_win4 + T - 1) / T, T, 0, stream>>>((int4*)winner, n_win4);

    ppscatter_vote<<<(n + T - 1) / T, T, 0, stream>>>(coords, n, winner);

    int n_out4 = out_size / 4;          // 16,777,216
    ppscatter_gather<<<n_out4 / T, T, 0, stream>>>(feat, winner, (nfloat4*)d_out);
}